// Round 21
// baseline (37.213 us; speedup 1.0000x reference)
//
#include <hip/hip_runtime.h>
#include <math.h>

#define SRATE   24000.0
#define NB      8
#define NT      48000
#define NH      60
#define NC      100
#define NFMT    5
#define CTS     64
#define NCH     (NT / CTS)       // 750 chunks per batch
#define TWO_PI  6.283185307179586476925286766559
#define PSC     (1.0f / 1024.0f) // exact 2^-10 prescale
#define NYQS    11.71875f        // 12000 * 2^-10

typedef float v2f __attribute__((ext_vector_type(2)));

// ---------------- kernel 1: per-chunk f0 sums (double) ----------------
__global__ __launch_bounds__(256) void k_partial(const float* __restrict__ f0,
                                                 double* __restrict__ part) {
    int b = blockIdx.y;
    int ch = blockIdx.x * 4 + (threadIdx.x >> 6);
    int lane = threadIdx.x & 63;
    if (ch < NCH) {
        int t = ch * CTS + lane;
        double q = (double)f0[b * NT + t];
        #pragma unroll
        for (int off = 32; off > 0; off >>= 1)
            q += __shfl_down(q, off, 64);
        if (lane == 0) part[b * NCH + ch] = q;
    }
}

// ---- kernel 2: per-timestep phase precompute -> prep[t]=(f0*2^-10, rev) ----
// One wave per chunk. Absorbs the ENTIRE serial preamble (part[] reduce,
// f64 butterflies, f32 scan) that previously sat on every k_main wave's
// critical path. Also writes final_phase (chunk 0).
__global__ __launch_bounds__(256) void k_rev(const float* __restrict__ f0,
                                             const double* __restrict__ part,
                                             const float* __restrict__ initp,
                                             float2* __restrict__ prep,
                                             float* __restrict__ outf) {
    int b = blockIdx.y;
    int ch = blockIdx.x * 4 + (threadIdx.x >> 6);
    int lane = threadIdx.x & 63;
    if (ch >= NCH) return;

    const double* pb = part + b * NCH;
    double sl = 0.0, sa = 0.0;
    #pragma unroll
    for (int k = 0; k < 12; ++k) {
        int idx = k * 64 + lane;
        double v = (idx < NCH) ? pb[idx] : 0.0;
        sa += v;
        if (idx < ch) sl += v;
    }
    #pragma unroll
    for (int off = 1; off < 64; off <<= 1) {
        sl += __shfl_xor(sl, off, 64);
        sa += __shfl_xor(sa, off, 64);
    }
    double initrev = (double)initp[b] * (1.0 / TWO_PI);
    if (ch == 0 && lane == 0) {
        double rv = sa * (1.0 / SRATE) + initrev;
        outf[b] = (float)((rv - floor(rv)) * TWO_PI);
    }
    double pfrac = sl * (1.0 / SRATE) + initrev;
    float prefF = (float)(pfrac - floor(pfrac));     // [0,1), wave-uniform

    int t = ch * CTS + lane;
    float f0v = f0[b * NT + t];
    float incf = f0v;
    #pragma unroll
    for (int off = 1; off < 64; off <<= 1) {
        float n = __shfl_up(incf, off, 64);
        if (lane >= off) incf += n;
    }
    float rev = __builtin_amdgcn_fractf(prefF + incf * (1.0f / 24000.0f));
    prep[(size_t)b * NT + t] = make_float2(f0v * PSC, rev);
}

// ---------------- kernel 3: main synthesis ----------------
// ONE WAVE = ONE PASS (16 ts x 4 lanes): 24000 waves -> ~23 waves/SIMD of
// work, deep enough to hide all load latency. Per-wave state is tiny
// (no LDS, no shuffles except the final 4-lane reduce, no f64): one 8B prep
// broadcast + 4 amp float4 + in-register lerp, then the pk formant pass.
__global__ __launch_bounds__(256) void k_main(const float2* __restrict__ prep,
                                              const float* __restrict__ amps,
                                              const float* __restrict__ ffq,
                                              const float* __restrict__ fbw,
                                              const float* __restrict__ fam,
                                              float* __restrict__ out) {
    int b = blockIdx.y;
    int ch = blockIdx.x;
    int wv = threadIdx.x >> 6;         // pass index 0..3
    int lane = threadIdx.x & 63;
    int g0 = lane >> 2, j = lane & 3;
    int t = ch * CTS + (wv << 4) + g0; // this lane-group's timestep

    // ---- loads: all independent, issue at entry ----
    const float4* rr = (const float4*)(amps + ((size_t)b * NT + t) * NH);
    float4 q0 = rr[j];
    float4 q1 = rr[4 + j];
    float4 q2 = rr[8 + j];
    float4 q3 = (j < 3) ? rr[12 + j] : make_float4(0.f, 0.f, 0.f, 0.f);
    float2 pr = prep[(size_t)b * NT + t];

    // ---- formant lerp for timestep t (in registers; 4-lane redundant) ----
    double srcd = (double)t * (99.0 / 47999.0);
    int i0 = (int)srcd;
    if (i0 > NC - 2) i0 = NC - 2;
    float frac = (float)(srcd - (double)i0);
    float omf = 1.0f - frac;
    const float* Fq = ffq + (b * NC + i0) * NFMT;
    const float* Bw = fbw + (b * NC + i0) * NFMT;
    const float* Am = fam + (b * NC + i0) * NFMT;
    float fq[NFMT], c1[NFMT], c2[NFMT];
    #pragma unroll
    for (int f = 0; f < NFMT; ++f) {
        float fqv = Fq[f] * omf + Fq[NFMT + f] * frac;
        float bwv = Bw[f] * omf + Bw[NFMT + f] * frac;
        float amv = Am[f] * omf + Am[NFMT + f] * frac;
        float bws = bwv * PSC;
        fq[f] = fqv * PSC;
        c2[f] = bws * bws;
        c1[f] = amv * c2[f];
    }

    float f0s   = pr.x;
    float rev_g = pr.y;

    // ---- one pass: lane j owns quads {4j+1..4j+4} + {0,16,32,48} ----
    float hb = (float)(j << 2);
    auto sd = [&](float k) {
        return __builtin_amdgcn_sinf(
            __builtin_amdgcn_fractf((hb + k) * rev_g));
    };
    v2f s01 = {sd(1.0f),  sd(2.0f)};
    v2f s23 = {sd(3.0f),  sd(4.0f)};
    v2f s45 = {sd(17.0f), sd(18.0f)};
    v2f s67 = {sd(19.0f), sd(20.0f)};
    float c16 = __builtin_amdgcn_cosf(
        __builtin_amdgcn_fractf(16.0f * rev_g));    // cos(16*theta)
    v2f cv = {2.0f * c16, 2.0f * c16};
    v2f s89 = cv * s45 - s01;                       // (hb+33,34)
    v2f sAB = cv * s67 - s23;                       // (hb+35,36)
    v2f sCD = cv * s89 - s45;                       // (hb+49,50)
    v2f sEF = cv * sAB - s67;                       // (hb+51,52)
    v2f acc2 = {0.0f, 0.0f};
    auto pairf = [&](float h1, v2f sn, float a0, float a1) {
        v2f hfl = {h1, h1 + 1.0f};
        v2f hs = f0s * hfl;                         // f0*h * 2^-10
        v2f d0 = hs - fq[0];
        v2f e0 = d0 * d0 + c2[0];
        v2f pN = e0 + c1[0];
        v2f pD = e0;
        #pragma unroll
        for (int f = 1; f < NFMT; ++f) {
            v2f d = hs - fq[f];
            v2f e = d * d + c2[f];
            pN *= e + c1[f];
            pD *= e;
        }
        float R = __builtin_amdgcn_rcpf(pD.x * pD.y);
        v2f fac = {pN.x * pD.y * R, pN.y * pD.x * R};
        v2f fm;
        fm.x = (hs.x < NYQS) ? fac.x : 0.0f;        // nyquist mask
        fm.y = (hs.y < NYQS) ? fac.y : 0.0f;
        v2f aa = {a0, a1};
        acc2 += (sn * aa) * fm;
    };
    pairf(hb + 1.0f,  s01, q0.x, q0.y);
    pairf(hb + 3.0f,  s23, q0.z, q0.w);
    pairf(hb + 17.0f, s45, q1.x, q1.y);
    pairf(hb + 19.0f, s67, q1.z, q1.w);
    pairf(hb + 33.0f, s89, q2.x, q2.y);
    pairf(hb + 35.0f, sAB, q2.z, q2.w);
    pairf(hb + 49.0f, sCD, q3.x, q3.y);
    pairf(hb + 51.0f, sEF, q3.z, q3.w);
    float acc = acc2.x + acc2.y;
    acc += __shfl_xor(acc, 1, 64);
    acc += __shfl_xor(acc, 2, 64);
    if (j == 0) {
        if (!(f0s > 0.0f)) acc = 0.0f;              // voiced mask
        out[b * NT + t] = acc;
    }
}

extern "C" void kernel_launch(void* const* d_in, const int* in_sizes, int n_in,
                              void* d_out, int out_size, void* d_ws, size_t ws_size,
                              hipStream_t stream) {
    const float* f0    = (const float*)d_in[0];
    const float* amps  = (const float*)d_in[1];
    const float* ffq   = (const float*)d_in[2];
    const float* fbw   = (const float*)d_in[3];
    const float* fam   = (const float*)d_in[4];
    const float* initp = (const float*)d_in[5];
    float* out = (float*)d_out;

    double* part = (double*)d_ws;                    // NB*NCH doubles (48 KB)
    float2* prep = (float2*)(part + NB * NCH);       // NB*NT float2 (3 MB)

    dim3 gchunk((NCH + 3) / 4, NB);
    k_partial<<<gchunk, 256, 0, stream>>>(f0, part);
    k_rev<<<gchunk, 256, 0, stream>>>(f0, part, initp, prep, out + NB * NT);
    dim3 gmain(NCH, NB);
    k_main<<<gmain, 256, 0, stream>>>(prep, amps, ffq, fbw, fam, out);
}